// Round 1
// baseline (846.886 us; speedup 1.0000x reference)
//
#include <hip/hip_runtime.h>
#include <math.h>

#define BB 2
#define NN 512
#define CSZ 384
#define HH 12
#define CC 16
#define PP 8
#define PVV 8
#define KG 16
#define GG 64
#define NCOL 912
#define NODES (BB*NN)

// ---------------- K0: weight prep ----------------
__global__ void k0_prep(const float* __restrict__ Wq, const float* __restrict__ Wkv,
                        const float* __restrict__ Wpq, const float* __restrict__ Wpv,
                        const float* __restrict__ Wkvp,
                        const float* __restrict__ bq, const float* __restrict__ bkv,
                        const float* __restrict__ bpq, const float* __restrict__ bpv,
                        const float* __restrict__ bkvp,
                        const float* __restrict__ ln_g, const float* __restrict__ ln_b,
                        const float* __restrict__ W1, const float* __restrict__ hwin,
                        float* __restrict__ Wbig, float* __restrict__ biasbig,
                        float* __restrict__ P2big, float* __restrict__ W1T,
                        float* __restrict__ hw)
{
  int idx = blockIdx.x*blockDim.x + threadIdx.x;
  int stride = gridDim.x*blockDim.x;
  for (int t = idx; t < CSZ*NCOL; t += stride) {
    int f = t / NCOL, c = t % NCOL;
    float w;
    if (c < 192)      w = Wq[f*192 + c];
    else if (c < 576) w = Wkv[f*384 + (c-192)];
    else if (c < 600) w = ln_g[f]*Wpq[f*24 + (c-576)];
    else if (c < 624) w = ln_g[f]*Wpv[f*24 + (c-600)];
    else              w = Wkvp[f*288 + (c-624)];
    Wbig[t] = w;
  }
  for (int t = idx; t < 64*64; t += stride) {
    int ho = t >> 6, kk = t & 63;
    W1T[t] = W1[kk*64 + ho];
  }
  for (int c = idx; c < NCOL; c += stride) {
    float bb, p2 = 0.f;
    if (c < 192)      bb = bq[c];
    else if (c < 576) bb = bkv[c-192];
    else if (c < 624) {
      const float* W = (c < 600) ? (Wpq + (c-576)) : (Wpv + (c-600));
      float p1 = 0.f;
      for (int f = 0; f < CSZ; ++f) { p1 += ln_b[f]*W[f*24]; p2 += ln_g[f]*W[f*24]; }
      bb = ((c < 600) ? bpq[c-576] : bpv[c-600]) + p1;
    }
    else bb = bkvp[c-624];
    biasbig[c] = bb; P2big[c] = p2;
  }
  for (int h = idx; h < HH; h += stride) {
    float x = hwin[h];
    float sp = (x > 20.f) ? x : log1pf(expf(x));
    hw[h] = sp * sqrtf(1.0f/18.0f) * -0.5f;   // AFS=4, AFS*4.5=18
  }
}

// ---------------- K0b: layernorm stats ----------------
__global__ void k0b_stats(const float* __restrict__ s, float* __restrict__ mout,
                          float* __restrict__ rstdout)
{
  int node = blockIdx.x;
  int l = threadIdx.x;                 // 64 threads = 1 wave
  const float* row = s + node*CSZ;
  float sum = 0.f, sum2 = 0.f;
  for (int f = l; f < CSZ; f += 64) { float v = row[f]; sum += v; sum2 += v*v; }
  #pragma unroll
  for (int off = 1; off < 64; off <<= 1) { sum += __shfl_xor(sum, off); sum2 += __shfl_xor(sum2, off); }
  if (l == 0) {
    float m = sum / CSZ;
    float var = sum2 / CSZ - m*m;
    mout[node] = m;
    rstdout[node] = rsqrtf(var + 1e-5f);
  }
}

// ---------------- K1: fused node GEMM ----------------
__launch_bounds__(256)
__global__ void k1_gemm(const float* __restrict__ s, const float* __restrict__ Wbig,
                        const float* __restrict__ biasbig, const float* __restrict__ P2big,
                        const float* __restrict__ mrow, const float* __restrict__ rstd,
                        float* __restrict__ act)
{
  const int ROWS = 4;
  int row0 = blockIdx.x * ROWS;   // grid 256
  int t = threadIdx.x;            // 256
  float acc[4][ROWS];
  #pragma unroll
  for (int j = 0; j < 4; ++j)
    #pragma unroll
    for (int r = 0; r < ROWS; ++r) acc[j][r] = 0.f;

  int c3 = t + 768;
  #pragma unroll 4
  for (int f = 0; f < CSZ; ++f) {
    const float* wrow = Wbig + f*NCOL;
    float w0 = wrow[t], w1 = wrow[t+256], w2 = wrow[t+512];
    float w3 = (c3 < NCOL) ? wrow[c3] : 0.f;
    #pragma unroll
    for (int r = 0; r < ROWS; ++r) {
      float sv = s[(row0+r)*CSZ + f];     // uniform -> scalar load
      acc[0][r] = fmaf(sv, w0, acc[0][r]);
      acc[1][r] = fmaf(sv, w1, acc[1][r]);
      acc[2][r] = fmaf(sv, w2, acc[2][r]);
      acc[3][r] = fmaf(sv, w3, acc[3][r]);
    }
  }
  #pragma unroll
  for (int j = 0; j < 4; ++j) {
    int c = t + j*256;
    if (c < NCOL) {
      float bb = biasbig[c], p2v = P2big[c];
      bool lncol = (c >= 576 && c < 624);
      #pragma unroll
      for (int r = 0; r < ROWS; ++r) {
        int node = row0 + r;
        float v;
        if (lncol) { float rs = rstd[node]; v = acc[j][r]*rs + bb - mrow[node]*rs*p2v; }
        else       v = acc[j][r] + bb;
        act[node*NCOL + c] = v;
      }
    }
  }
}

// ---------------- K1b: v transpose + vg compute ----------------
__global__ void k1b_post(const float* __restrict__ act, const float* __restrict__ rot,
                         const float* __restrict__ trans,
                         float* __restrict__ vT, float* __restrict__ vgT)
{
  int idx = blockIdx.x*blockDim.x + threadIdx.x;
  const int NT1 = BB*HH*CC*NN;       // 196608
  const int NT2 = BB*HH*PVV*3*NN;    // 294912
  if (idx < NT1) {
    int n = idx & (NN-1); int rest = idx >> 9;
    int c = rest & 15; rest >>= 4;
    int h = rest % HH; int b = rest / HH;
    int node = b*NN + n;
    vT[idx] = act[node*NCOL + 192 + h*32 + 16 + c];
  } else if (idx < NT1 + NT2) {
    int j = idx - NT1;
    int n = j & (NN-1); int rest = j >> 9;
    int p3 = rest % 24; rest /= 24;
    int h = rest % HH; int b = rest / HH;
    int node = b*NN + n;
    int p = p3 / 3, x = p3 % 3;
    int hp = h*PVV + p;
    const float* kp = act + node*NCOL + 624 + hp*3;
    const float* R = rot + node*9;
    vgT[j] = R[x*3+0]*kp[0] + R[x*3+1]*kp[1] + R[x*3+2]*kp[2] + trans[node*3+x]*0.1f;
  }
}

// ---------------- K2: fused pair kernel (dominant) ----------------
__global__ void k2_pair(const float* __restrict__ act, const float* __restrict__ rot,
                        const float* __restrict__ trans, const float* __restrict__ mask,
                        const float* __restrict__ Wvl, const float* __restrict__ gm_in,
                        const float* __restrict__ gs_in,
                        const float* __restrict__ Wg, const float* __restrict__ bg,
                        const float* __restrict__ W1T, const float* __restrict__ b1,
                        const float* __restrict__ W2, const float* __restrict__ b2,
                        const float* __restrict__ hw,
                        float* __restrict__ gout, float* __restrict__ apre)
{
  __shared__ float s_qvec[PP*3];
  __shared__ float s_gm[KG], s_gis[KG];
  __shared__ float s_hw[HH];

  int bi = blockIdx.x;            // = b*NN + i
  int b = bi >> 9, i = bi & (NN-1);
  int t = threadIdx.x;
  const float* acti = act + bi*NCOL;

  if (t < 24) {
    int o = t / 3, c = t % 3;
    float sum = 0.f;
    #pragma unroll
    for (int p = 0; p < PP; ++p) sum += Wvl[o*16 + 8 + p] * acti[576 + p*3 + c];
    s_qvec[t] = sum;
  } else if (t >= 32 && t < 48) {
    int k = t - 32; s_gm[k] = gm_in[k]; s_gis[k] = 1.f / gs_in[k];
  } else if (t >= 64 && t < 76) {
    s_hw[t-64] = hw[t-64];
  }
  __syncthreads();

  // block-uniform (scalar) data
  const float* Ri = rot + bi*9;
  float ri[9];
  #pragma unroll
  for (int q = 0; q < 9; ++q) ri[q] = Ri[q];
  float ti0 = trans[bi*3], ti1 = trans[bi*3+1], ti2 = trans[bi*3+2];
  float mi = mask[bi];

  #pragma unroll 1
  for (int jj = 0; jj < 2; ++jj) {
    int j = t + jj*256;
    int jnode = b*NN + j;
    const float* actj = act + jnode*NCOL;

    const float* Rj = rot + jnode*9;
    float rj[9];
    #pragma unroll
    for (int q = 0; q < 9; ++q) rj[q] = Rj[q];
    float tj0 = trans[jnode*3], tj1 = trans[jnode*3+1], tj2 = trans[jnode*3+2];

    float Rr[9];
    #pragma unroll
    for (int x = 0; x < 3; ++x)
      #pragma unroll
      for (int z = 0; z < 3; ++z)
        Rr[x*3+z] = ri[x]*rj[z] + ri[3+x]*rj[3+z] + ri[6+x]*rj[6+z];

    float d0 = tj0-ti0, d1 = tj1-ti1, d2 = tj2-ti2;
    float tr[3];
    #pragma unroll
    for (int x = 0; x < 3; ++x) tr[x] = ri[x]*d0 + ri[3+x]*d1 + ri[6+x]*d2;

    float vp[24];
    {
      const float4* v4 = (const float4*)(actj + 600);
      #pragma unroll
      for (int q = 0; q < 6; ++q) {
        float4 x4 = v4[q];
        vp[q*4+0] = x4.x; vp[q*4+1] = x4.y; vp[q*4+2] = x4.z; vp[q*4+3] = x4.w;
      }
    }
    float vl[24];
    #pragma unroll
    for (int p = 0; p < PP; ++p)
      #pragma unroll
      for (int x = 0; x < 3; ++x)
        vl[p*3+x] = fmaf(Rr[x*3], vp[p*3], fmaf(Rr[x*3+1], vp[p*3+1], fmaf(Rr[x*3+2], vp[p*3+2], tr[x])));

    float vlen[8];
    #pragma unroll
    for (int o = 0; o < 8; ++o) {
      float vx = vl[o*3+0] + s_qvec[o*3+0];
      float vy = vl[o*3+1] + s_qvec[o*3+1];
      float vz = vl[o*3+2] + s_qvec[o*3+2];
      #pragma unroll
      for (int p = 0; p < PP; ++p) {
        float w = Wvl[o*16+p];    // uniform -> scalar
        vx = fmaf(w, vl[p*3+0], vx);
        vy = fmaf(w, vl[p*3+1], vy);
        vz = fmaf(w, vl[p*3+2], vz);
      }
      vlen[o] = sqrtf(vx*vx + vy*vy + vz*vz + 1e-8f);
    }

    float accg[64];
    #pragma unroll
    for (int q = 0; q < 64; ++q) accg[q] = bg[q];
    #pragma unroll
    for (int o = 0; o < 8; ++o) {
      #pragma unroll 1
      for (int k = 0; k < KG; ++k) {
        float tt = (vlen[o] - s_gm[k]) * s_gis[k];
        float gk = __expf(-0.5f * tt * tt);
        const float* wr = Wg + (o*KG + k)*64;   // uniform row -> scalar loads
        #pragma unroll
        for (int q = 0; q < 64; ++q) accg[q] = fmaf(gk, wr[q], accg[q]);
      }
    }

    // write g (output 1)
    {
      float4* gp4 = (float4*)(gout + ((size_t)bi*NN + j)*64);
      #pragma unroll
      for (int q = 0; q < 16; ++q)
        gp4[q] = make_float4(accg[4*q], accg[4*q+1], accg[4*q+2], accg[4*q+3]);
    }

    // vfn = relu(g@W1+b1)@W2 + b2
    float vf[12];
    #pragma unroll
    for (int hh = 0; hh < 12; ++hh) vf[hh] = b2[hh];
    #pragma unroll 1
    for (int ho = 0; ho < 64; ++ho) {
      const float* w1r = W1T + ho*64;
      float hs = b1[ho];
      #pragma unroll
      for (int q = 0; q < 64; ++q) hs = fmaf(accg[q], w1r[q], hs);
      hs = fmaxf(hs, 0.f);
      const float* w2r = W2 + ho*12;
      #pragma unroll
      for (int hh = 0; hh < 12; ++hh) vf[hh] = fmaf(hs, w2r[hh], vf[hh]);
    }

    // qk
    float qk[12];
    #pragma unroll
    for (int h = 0; h < 12; ++h) {
      const float4* k4 = (const float4*)(actj + 192 + h*32);
      float a = 0.f;
      #pragma unroll
      for (int q = 0; q < 4; ++q) {
        float4 kv = k4[q];
        const float* qp = acti + h*16 + q*4;   // uniform -> scalar
        a = fmaf(qp[0], kv.x, a); a = fmaf(qp[1], kv.y, a);
        a = fmaf(qp[2], kv.z, a); a = fmaf(qp[3], kv.w, a);
      }
      qk[h] = a;
    }

    float pd = 0.01f * (d0*d0 + d1*d1 + d2*d2);   // |coord_j - coord_i|^2, coord=trans*0.1
    float mj = mask[jnode];
    float mterm = 100000.f * (mi*mj - 1.f);
    #pragma unroll
    for (int h = 0; h < 12; ++h) {
      float v = qk[h]*0.125f + vf[h]*0.5f + pd*s_hw[h] + mterm;
      apre[(((size_t)b*HH + h)*NN + i)*NN + j] = v;
    }
  }
}

// ---------------- K3: softmax + attend ----------------
__launch_bounds__(256)
__global__ void k3_attend(const float* __restrict__ apre, const float* __restrict__ vT,
                          const float* __restrict__ vgT,
                          float* __restrict__ oout, float* __restrict__ optout)
{
  __shared__ float a4[NN][4];
  int blk = blockIdx.x;            // B*H*(N/4)
  int ic = blk & 127; int rest = blk >> 7;
  int h = rest % HH; int b = rest / HH;
  int i0 = ic * 4;
  int t = threadIdx.x; int w = t >> 6; int l = t & 63;

  { // phase 1: wave w -> row i0+w
    int i = i0 + w;
    const float* row = apre + (((size_t)b*HH + h)*NN + i)*NN;
    float vals[8];
    float m = -1e30f;
    #pragma unroll
    for (int s8 = 0; s8 < 8; ++s8) { vals[s8] = row[l + 64*s8]; m = fmaxf(m, vals[s8]); }
    #pragma unroll
    for (int off = 1; off < 64; off <<= 1) m = fmaxf(m, __shfl_xor(m, off));
    float sum = 0.f;
    #pragma unroll
    for (int s8 = 0; s8 < 8; ++s8) { vals[s8] = __expf(vals[s8] - m); sum += vals[s8]; }
    #pragma unroll
    for (int off = 1; off < 64; off <<= 1) sum += __shfl_xor(sum, off);
    float inv = 1.f / sum;
    #pragma unroll
    for (int s8 = 0; s8 < 8; ++s8) a4[l + 64*s8][w] = vals[s8] * inv;
  }
  __syncthreads();

  const float* vbase = vT + ((size_t)(b*HH + h)*CC)*NN;
  const float* gbase = vgT + ((size_t)(b*HH + h)*24)*NN;
  #pragma unroll 1
  for (int pass = 0; pass < 5; ++pass) {
    int c0 = w + 8*pass;
    int c1 = c0 + 4;
    const float* s0 = (c0 < 16) ? (vbase + c0*NN) : (gbase + (c0-16)*NN);
    const float* s1 = (c1 < 16) ? (vbase + c1*NN) : (gbase + (c1-16)*NN);
    float acc0[4] = {0,0,0,0}, acc1[4] = {0,0,0,0};
    #pragma unroll
    for (int s8 = 0; s8 < 8; ++s8) {
      int j = l + 64*s8;
      float4 av = *(const float4*)(&a4[j][0]);
      float v0 = s0[j], v1 = s1[j];
      acc0[0] = fmaf(av.x, v0, acc0[0]); acc0[1] = fmaf(av.y, v0, acc0[1]);
      acc0[2] = fmaf(av.z, v0, acc0[2]); acc0[3] = fmaf(av.w, v0, acc0[3]);
      acc1[0] = fmaf(av.x, v1, acc1[0]); acc1[1] = fmaf(av.y, v1, acc1[1]);
      acc1[2] = fmaf(av.z, v1, acc1[2]); acc1[3] = fmaf(av.w, v1, acc1[3]);
    }
    #pragma unroll
    for (int r = 0; r < 4; ++r) {
      #pragma unroll
      for (int off = 1; off < 64; off <<= 1) {
        acc0[r] += __shfl_xor(acc0[r], off);
        acc1[r] += __shfl_xor(acc1[r], off);
      }
    }
    if (l == 0) {
      #pragma unroll
      for (int r = 0; r < 4; ++r) {
        int node = b*NN + i0 + r;
        if (c0 < 16) oout[node*192 + h*16 + c0] = acc0[r];
        else         optout[node*288 + h*24 + (c0-16)] = acc0[r];
        if (c1 < 16) oout[node*192 + h*16 + c1] = acc1[r];
        else         optout[node*288 + h*24 + (c1-16)] = acc1[r];
      }
    }
  }
}

// ---------------- K4a: build feats ----------------
__global__ void k4a_feats(const float* __restrict__ oo, const float* __restrict__ opt,
                          const float* __restrict__ rot, const float* __restrict__ trans,
                          float* __restrict__ feats)
{
  int node = blockIdx.x; int t = threadIdx.x;   // 320 threads
  float* fr = feats + node*576;
  if (t < 192) {
    fr[t] = oo[node*192 + t];
  } else if (t < 288) {
    int hp = t - 192;
    const float* R = rot + node*9;
    float tx = trans[node*3+0]*0.1f, ty = trans[node*3+1]*0.1f, tz = trans[node*3+2]*0.1f;
    const float* op = opt + (node*96 + hp)*3;
    float px = op[0]-tx, py = op[1]-ty, pz = op[2]-tz;
    float lx = R[0]*px + R[3]*py + R[6]*pz;
    float ly = R[1]*px + R[4]*py + R[7]*pz;
    float lz = R[2]*px + R[5]*py + R[8]*pz;
    float d = sqrtf(lx*lx + ly*ly + lz*lz + 1e-8f);
    fr[192+hp] = lx; fr[288+hp] = ly; fr[384+hp] = lz; fr[480+hp] = d;
  }
}

// ---------------- K4b: output projection ----------------
__launch_bounds__(384)
__global__ void k4b_out(const float* __restrict__ feats, const float* __restrict__ Wout,
                        const float* __restrict__ bout, float* __restrict__ sout)
{
  const int ROWS = 8;
  int row0 = blockIdx.x * ROWS;   // grid 128
  int c = threadIdx.x;            // 384
  float acc[ROWS];
  #pragma unroll
  for (int r = 0; r < ROWS; ++r) acc[r] = 0.f;
  #pragma unroll 4
  for (int f = 0; f < 576; ++f) {
    float wv = Wout[f*384 + c];
    #pragma unroll
    for (int r = 0; r < ROWS; ++r)
      acc[r] = fmaf(feats[(row0+r)*576 + f], wv, acc[r]);   // feats uniform -> scalar
  }
  float bb = bout[c];
  #pragma unroll
  for (int r = 0; r < ROWS; ++r) sout[(row0+r)*384 + c] = acc[r] + bb;
}

// ---------------- launch ----------------
extern "C" void kernel_launch(void* const* d_in, const int* in_sizes, int n_in,
                              void* d_out, int out_size, void* d_ws, size_t ws_size,
                              hipStream_t stream)
{
  const float* s     = (const float*)d_in[0];
  const float* rot   = (const float*)d_in[1];
  const float* trans = (const float*)d_in[2];
  const float* mask  = (const float*)d_in[3];
  const float* Wq    = (const float*)d_in[4];
  const float* bq    = (const float*)d_in[5];
  const float* Wkv   = (const float*)d_in[6];
  const float* bkv   = (const float*)d_in[7];
  const float* hwts  = (const float*)d_in[8];
  const float* ln_g  = (const float*)d_in[9];
  const float* ln_b  = (const float*)d_in[10];
  const float* Wpq   = (const float*)d_in[11];
  const float* bpq   = (const float*)d_in[12];
  const float* Wpv   = (const float*)d_in[13];
  const float* bpv   = (const float*)d_in[14];
  const float* Wvl   = (const float*)d_in[15];
  const float* gbm   = (const float*)d_in[16];
  const float* gbs   = (const float*)d_in[17];
  const float* Wg    = (const float*)d_in[18];
  const float* bg    = (const float*)d_in[19];
  const float* W1    = (const float*)d_in[20];
  const float* b1    = (const float*)d_in[21];
  const float* W2    = (const float*)d_in[22];
  const float* b2    = (const float*)d_in[23];
  const float* Wkvp  = (const float*)d_in[24];
  const float* bkvp  = (const float*)d_in[25];
  const float* Wout  = (const float*)d_in[26];
  const float* bout  = (const float*)d_in[27];

  float* ws = (float*)d_ws;
  float* act   = ws + 0;          // 1024*912
  float* Wbig  = ws + 933888;     // 384*912
  float* bias  = ws + 1284096;    // 912
  float* P2    = ws + 1285008;    // 912
  float* W1T   = ws + 1285920;    // 4096
  float* hw    = ws + 1290016;    // 16
  float* mrow  = ws + 1290032;    // 1024
  float* rstd  = ws + 1291056;    // 1024
  float* vT    = ws + 1292080;    // 196608
  float* vgT   = ws + 1488688;    // 294912
  float* apre  = ws + 1783600;    // 6291456
  float* oo    = ws + 8075056;    // 196608
  float* opt   = ws + 8271664;    // 294912
  float* feats = ws + 8566576;    // 589824  (end 9156400 floats = 36.6 MB)

  float* sout = (float*)d_out;
  float* gout = sout + BB*NN*CSZ;   // g at offset 393216

  hipLaunchKernelGGL(k0_prep, dim3(256), dim3(256), 0, stream,
                     Wq, Wkv, Wpq, Wpv, Wkvp, bq, bkv, bpq, bpv, bkvp,
                     ln_g, ln_b, W1, hwts, Wbig, bias, P2, W1T, hw);
  hipLaunchKernelGGL(k0b_stats, dim3(1024), dim3(64), 0, stream, s, mrow, rstd);
  hipLaunchKernelGGL(k1_gemm, dim3(256), dim3(256), 0, stream,
                     s, Wbig, bias, P2, mrow, rstd, act);
  hipLaunchKernelGGL(k1b_post, dim3(1920), dim3(256), 0, stream, act, rot, trans, vT, vgT);
  hipLaunchKernelGGL(k2_pair, dim3(1024), dim3(256), 0, stream,
                     act, rot, trans, mask, Wvl, gbm, gbs, Wg, bg, W1T, b1, W2, b2, hw,
                     gout, apre);
  hipLaunchKernelGGL(k3_attend, dim3(3072), dim3(256), 0, stream, apre, vT, vgT, oo, opt);
  hipLaunchKernelGGL(k4a_feats, dim3(1024), dim3(320), 0, stream, oo, opt, rot, trans, feats);
  hipLaunchKernelGGL(k4b_out, dim3(128), dim3(384), 0, stream, feats, Wout, bout, sout);
}

// Round 2
// 717.929 us; speedup vs baseline: 1.1796x; 1.1796x over previous
//
#include <hip/hip_runtime.h>
#include <math.h>

#define BB 2
#define NN 512
#define CSZ 384
#define HH 12
#define CC 16
#define PP 8
#define PVV 8
#define KG 16
#define GG 64
#define NCOL 912
#define NODES (BB*NN)

// ---------------- K0: weight prep ----------------
__global__ void k0_prep(const float* __restrict__ Wq, const float* __restrict__ Wkv,
                        const float* __restrict__ Wpq, const float* __restrict__ Wpv,
                        const float* __restrict__ Wkvp,
                        const float* __restrict__ bq, const float* __restrict__ bkv,
                        const float* __restrict__ bpq, const float* __restrict__ bpv,
                        const float* __restrict__ bkvp,
                        const float* __restrict__ ln_g, const float* __restrict__ ln_b,
                        const float* __restrict__ W1, const float* __restrict__ hwin,
                        float* __restrict__ Wbig, float* __restrict__ biasbig,
                        float* __restrict__ P2big, float* __restrict__ W1T,
                        float* __restrict__ hw)
{
  int idx = blockIdx.x*blockDim.x + threadIdx.x;
  int stride = gridDim.x*blockDim.x;
  for (int t = idx; t < CSZ*NCOL; t += stride) {
    int f = t / NCOL, c = t % NCOL;
    float w;
    if (c < 192)      w = Wq[f*192 + c];
    else if (c < 576) w = Wkv[f*384 + (c-192)];
    else if (c < 600) w = ln_g[f]*Wpq[f*24 + (c-576)];
    else if (c < 624) w = ln_g[f]*Wpv[f*24 + (c-600)];
    else              w = Wkvp[f*288 + (c-624)];
    Wbig[t] = w;
  }
  for (int t = idx; t < 64*64; t += stride) {
    int ho = t >> 6, kk = t & 63;
    W1T[t] = W1[kk*64 + ho];
  }
  for (int c = idx; c < NCOL; c += stride) {
    float bb, p2 = 0.f;
    if (c < 192)      bb = bq[c];
    else if (c < 576) bb = bkv[c-192];
    else if (c < 624) {
      const float* W = (c < 600) ? (Wpq + (c-576)) : (Wpv + (c-600));
      float p1 = 0.f;
      for (int f = 0; f < CSZ; ++f) { p1 += ln_b[f]*W[f*24]; p2 += ln_g[f]*W[f*24]; }
      bb = ((c < 600) ? bpq[c-576] : bpv[c-600]) + p1;
    }
    else bb = bkvp[c-624];
    biasbig[c] = bb; P2big[c] = p2;
  }
  for (int h = idx; h < HH; h += stride) {
    float x = hwin[h];
    float sp = (x > 20.f) ? x : log1pf(expf(x));
    hw[h] = sp * sqrtf(1.0f/18.0f) * -0.5f;   // AFS=4, AFS*4.5=18
  }
}

// ---------------- K0b: layernorm stats ----------------
__global__ void k0b_stats(const float* __restrict__ s, float* __restrict__ mout,
                          float* __restrict__ rstdout)
{
  int node = blockIdx.x;
  int l = threadIdx.x;                 // 64 threads = 1 wave
  const float* row = s + node*CSZ;
  float sum = 0.f, sum2 = 0.f;
  for (int f = l; f < CSZ; f += 64) { float v = row[f]; sum += v; sum2 += v*v; }
  #pragma unroll
  for (int off = 1; off < 64; off <<= 1) { sum += __shfl_xor(sum, off); sum2 += __shfl_xor(sum2, off); }
  if (l == 0) {
    float m = sum / CSZ;
    float var = sum2 / CSZ - m*m;
    mout[node] = m;
    rstdout[node] = rsqrtf(var + 1e-5f);
  }
}

// ---------------- K1: fused node GEMM ----------------
__launch_bounds__(256)
__global__ void k1_gemm(const float* __restrict__ s, const float* __restrict__ Wbig,
                        const float* __restrict__ biasbig, const float* __restrict__ P2big,
                        const float* __restrict__ mrow, const float* __restrict__ rstd,
                        float* __restrict__ act)
{
  const int ROWS = 8;
  int row0 = blockIdx.x * ROWS;   // grid 128
  int t = threadIdx.x;            // 256
  float acc[4][ROWS];
  #pragma unroll
  for (int j = 0; j < 4; ++j)
    #pragma unroll
    for (int r = 0; r < ROWS; ++r) acc[j][r] = 0.f;

  int c3 = t + 768;
  #pragma unroll 4
  for (int f = 0; f < CSZ; ++f) {
    const float* wrow = Wbig + f*NCOL;
    float w0 = wrow[t], w1 = wrow[t+256], w2 = wrow[t+512];
    float w3 = (c3 < NCOL) ? wrow[c3] : 0.f;
    #pragma unroll
    for (int r = 0; r < ROWS; ++r) {
      float sv = s[(row0+r)*CSZ + f];     // uniform -> scalar load
      acc[0][r] = fmaf(sv, w0, acc[0][r]);
      acc[1][r] = fmaf(sv, w1, acc[1][r]);
      acc[2][r] = fmaf(sv, w2, acc[2][r]);
      acc[3][r] = fmaf(sv, w3, acc[3][r]);
    }
  }
  #pragma unroll
  for (int j = 0; j < 4; ++j) {
    int c = t + j*256;
    if (c < NCOL) {
      float bb = biasbig[c], p2v = P2big[c];
      bool lncol = (c >= 576 && c < 624);
      #pragma unroll
      for (int r = 0; r < ROWS; ++r) {
        int node = row0 + r;
        float v;
        if (lncol) { float rs = rstd[node]; v = acc[j][r]*rs + bb - mrow[node]*rs*p2v; }
        else       v = acc[j][r] + bb;
        act[node*NCOL + c] = v;
      }
    }
  }
}

// ---------------- K1b: v transpose + vg compute ----------------
__global__ void k1b_post(const float* __restrict__ act, const float* __restrict__ rot,
                         const float* __restrict__ trans,
                         float* __restrict__ vT, float* __restrict__ vgT)
{
  int idx = blockIdx.x*blockDim.x + threadIdx.x;
  const int NT1 = BB*HH*CC*NN;       // 196608
  const int NT2 = BB*HH*PVV*3*NN;    // 294912
  if (idx < NT1) {
    int n = idx & (NN-1); int rest = idx >> 9;
    int c = rest & 15; rest >>= 4;
    int h = rest % HH; int b = rest / HH;
    int node = b*NN + n;
    vT[idx] = act[node*NCOL + 192 + h*32 + 16 + c];
  } else if (idx < NT1 + NT2) {
    int j = idx - NT1;
    int n = j & (NN-1); int rest = j >> 9;
    int p3 = rest % 24; rest /= 24;
    int h = rest % HH; int b = rest / HH;
    int node = b*NN + n;
    int p = p3 / 3, x = p3 % 3;
    int hp = h*PVV + p;
    const float* kp = act + node*NCOL + 624 + hp*3;
    const float* R = rot + node*9;
    vgT[j] = R[x*3+0]*kp[0] + R[x*3+1]*kp[1] + R[x*3+2]*kp[2] + trans[node*3+x]*0.1f;
  }
}

// ---------------- K2: fused pair kernel (dominant) ----------------
__global__ void k2_pair(const float* __restrict__ act, const float* __restrict__ rot,
                        const float* __restrict__ trans, const float* __restrict__ mask,
                        const float* __restrict__ Wvl, const float* __restrict__ gm_in,
                        const float* __restrict__ gs_in,
                        const float* __restrict__ Wg, const float* __restrict__ bg,
                        const float* __restrict__ W1T, const float* __restrict__ b1,
                        const float* __restrict__ W2, const float* __restrict__ b2,
                        const float* __restrict__ hw,
                        float* __restrict__ gout, float* __restrict__ apre)
{
  __shared__ float s_qvec[PP*3];
  __shared__ float s_gm[KG], s_gis[KG];
  __shared__ float s_hw[HH];

  int blk = blockIdx.x;           // grid 2048: (bi, jj)
  int bi = blk >> 1;
  int jj = blk & 1;
  int b = bi >> 9, i = bi & (NN-1);
  int t = threadIdx.x;
  const float* acti = act + bi*NCOL;

  if (t < 24) {
    int o = t / 3, c = t % 3;
    float sum = 0.f;
    #pragma unroll
    for (int p = 0; p < PP; ++p) sum += Wvl[o*16 + 8 + p] * acti[576 + p*3 + c];
    s_qvec[t] = sum;
  } else if (t >= 32 && t < 48) {
    int k = t - 32; s_gm[k] = gm_in[k]; s_gis[k] = 1.f / gs_in[k];
  } else if (t >= 64 && t < 76) {
    s_hw[t-64] = hw[t-64];
  }
  __syncthreads();

  // block-uniform (scalar) data
  const float* Ri = rot + bi*9;
  float ri[9];
  #pragma unroll
  for (int q = 0; q < 9; ++q) ri[q] = Ri[q];
  float ti0 = trans[bi*3], ti1 = trans[bi*3+1], ti2 = trans[bi*3+2];
  float mi = mask[bi];

  int j = t + jj*256;
  int jnode = b*NN + j;
  const float* actj = act + jnode*NCOL;

  const float* Rj = rot + jnode*9;
  float rj[9];
  #pragma unroll
  for (int q = 0; q < 9; ++q) rj[q] = Rj[q];
  float tj0 = trans[jnode*3], tj1 = trans[jnode*3+1], tj2 = trans[jnode*3+2];

  float Rr[9];
  #pragma unroll
  for (int x = 0; x < 3; ++x)
    #pragma unroll
    for (int z = 0; z < 3; ++z)
      Rr[x*3+z] = ri[x]*rj[z] + ri[3+x]*rj[3+z] + ri[6+x]*rj[6+z];

  float d0 = tj0-ti0, d1 = tj1-ti1, d2 = tj2-ti2;
  float tr[3];
  #pragma unroll
  for (int x = 0; x < 3; ++x) tr[x] = ri[x]*d0 + ri[3+x]*d1 + ri[6+x]*d2;

  float vp[24];
  {
    const float4* v4 = (const float4*)(actj + 600);
    #pragma unroll
    for (int q = 0; q < 6; ++q) {
      float4 x4 = v4[q];
      vp[q*4+0] = x4.x; vp[q*4+1] = x4.y; vp[q*4+2] = x4.z; vp[q*4+3] = x4.w;
    }
  }
  float vl[24];
  #pragma unroll
  for (int p = 0; p < PP; ++p)
    #pragma unroll
    for (int x = 0; x < 3; ++x)
      vl[p*3+x] = fmaf(Rr[x*3], vp[p*3], fmaf(Rr[x*3+1], vp[p*3+1], fmaf(Rr[x*3+2], vp[p*3+2], tr[x])));

  float vlen[8];
  #pragma unroll
  for (int o = 0; o < 8; ++o) {
    float vx = vl[o*3+0] + s_qvec[o*3+0];
    float vy = vl[o*3+1] + s_qvec[o*3+1];
    float vz = vl[o*3+2] + s_qvec[o*3+2];
    #pragma unroll
    for (int p = 0; p < PP; ++p) {
      float w = Wvl[o*16+p];    // uniform -> scalar
      vx = fmaf(w, vl[p*3+0], vx);
      vy = fmaf(w, vl[p*3+1], vy);
      vz = fmaf(w, vl[p*3+2], vz);
    }
    vlen[o] = sqrtf(vx*vx + vy*vy + vz*vz + 1e-8f);
  }

  float accg[64];
  #pragma unroll
  for (int q = 0; q < 64; ++q) accg[q] = bg[q];
  #pragma unroll 1
  for (int o = 0; o < 8; ++o) {
    // precompute 16 gaussian weights for this o (keeps exp off the FMA loop)
    float gv[KG];
    #pragma unroll
    for (int k = 0; k < KG; ++k) {
      float tt = (vlen[o] - s_gm[k]) * s_gis[k];
      gv[k] = __expf(-0.5f * tt * tt);
    }
    const float* wbase = Wg + o*KG*64;
    #pragma unroll 2
    for (int k = 0; k < KG; ++k) {
      float gk = gv[k];
      const float* wr = wbase + k*64;   // uniform row -> scalar loads
      #pragma unroll
      for (int q = 0; q < 64; ++q) accg[q] = fmaf(gk, wr[q], accg[q]);
    }
  }

  // write g (output 1)
  {
    float4* gp4 = (float4*)(gout + ((size_t)bi*NN + j)*64);
    #pragma unroll
    for (int q = 0; q < 16; ++q)
      gp4[q] = make_float4(accg[4*q], accg[4*q+1], accg[4*q+2], accg[4*q+3]);
  }

  // vfn = relu(g@W1+b1)@W2 + b2
  float vf[12];
  #pragma unroll
  for (int hh = 0; hh < 12; ++hh) vf[hh] = b2[hh];
  #pragma unroll 2
  for (int ho = 0; ho < 64; ++ho) {
    const float* w1r = W1T + ho*64;
    // 4 partial accumulators -> dependent chain length 16 instead of 64
    float h0 = b1[ho], h1 = 0.f, h2 = 0.f, h3 = 0.f;
    #pragma unroll
    for (int q = 0; q < 16; ++q) {
      h0 = fmaf(accg[q],      w1r[q],      h0);
      h1 = fmaf(accg[q+16],   w1r[q+16],   h1);
      h2 = fmaf(accg[q+32],   w1r[q+32],   h2);
      h3 = fmaf(accg[q+48],   w1r[q+48],   h3);
    }
    float hs = fmaxf((h0+h1) + (h2+h3), 0.f);
    const float* w2r = W2 + ho*12;
    #pragma unroll
    for (int hh = 0; hh < 12; ++hh) vf[hh] = fmaf(hs, w2r[hh], vf[hh]);
  }

  // qk
  float qk[12];
  #pragma unroll
  for (int h = 0; h < 12; ++h) {
    const float4* k4 = (const float4*)(actj + 192 + h*32);
    float a = 0.f;
    #pragma unroll
    for (int q = 0; q < 4; ++q) {
      float4 kv = k4[q];
      const float* qp = acti + h*16 + q*4;   // uniform -> scalar
      a = fmaf(qp[0], kv.x, a); a = fmaf(qp[1], kv.y, a);
      a = fmaf(qp[2], kv.z, a); a = fmaf(qp[3], kv.w, a);
    }
    qk[h] = a;
  }

  float pd = 0.01f * (d0*d0 + d1*d1 + d2*d2);   // |coord_j - coord_i|^2, coord=trans*0.1
  float mj = mask[jnode];
  float mterm = 100000.f * (mi*mj - 1.f);
  #pragma unroll
  for (int h = 0; h < 12; ++h) {
    float v = qk[h]*0.125f + vf[h]*0.5f + pd*s_hw[h] + mterm;
    apre[(((size_t)b*HH + h)*NN + i)*NN + j] = v;
  }
}

// ---------------- K3: softmax + attend ----------------
__launch_bounds__(256)
__global__ void k3_attend(const float* __restrict__ apre, const float* __restrict__ vT,
                          const float* __restrict__ vgT,
                          float* __restrict__ oout, float* __restrict__ optout)
{
  __shared__ float a4[NN][4];
  int blk = blockIdx.x;            // B*H*(N/4)
  int ic = blk & 127; int rest = blk >> 7;
  int h = rest % HH; int b = rest / HH;
  int i0 = ic * 4;
  int t = threadIdx.x; int w = t >> 6; int l = t & 63;

  { // phase 1: wave w -> row i0+w
    int i = i0 + w;
    const float* row = apre + (((size_t)b*HH + h)*NN + i)*NN;
    float vals[8];
    float m = -1e30f;
    #pragma unroll
    for (int s8 = 0; s8 < 8; ++s8) { vals[s8] = row[l + 64*s8]; m = fmaxf(m, vals[s8]); }
    #pragma unroll
    for (int off = 1; off < 64; off <<= 1) m = fmaxf(m, __shfl_xor(m, off));
    float sum = 0.f;
    #pragma unroll
    for (int s8 = 0; s8 < 8; ++s8) { vals[s8] = __expf(vals[s8] - m); sum += vals[s8]; }
    #pragma unroll
    for (int off = 1; off < 64; off <<= 1) sum += __shfl_xor(sum, off);
    float inv = 1.f / sum;
    #pragma unroll
    for (int s8 = 0; s8 < 8; ++s8) a4[l + 64*s8][w] = vals[s8] * inv;
  }
  __syncthreads();

  const float* vbase = vT + ((size_t)(b*HH + h)*CC)*NN;
  const float* gbase = vgT + ((size_t)(b*HH + h)*24)*NN;
  #pragma unroll 1
  for (int pass = 0; pass < 5; ++pass) {
    int c0 = w + 8*pass;
    int c1 = c0 + 4;
    const float* s0 = (c0 < 16) ? (vbase + c0*NN) : (gbase + (c0-16)*NN);
    const float* s1 = (c1 < 16) ? (vbase + c1*NN) : (gbase + (c1-16)*NN);
    float acc0[4] = {0,0,0,0}, acc1[4] = {0,0,0,0};
    #pragma unroll
    for (int s8 = 0; s8 < 8; ++s8) {
      int j = l + 64*s8;
      float4 av = *(const float4*)(&a4[j][0]);
      float v0 = s0[j], v1 = s1[j];
      acc0[0] = fmaf(av.x, v0, acc0[0]); acc0[1] = fmaf(av.y, v0, acc0[1]);
      acc0[2] = fmaf(av.z, v0, acc0[2]); acc0[3] = fmaf(av.w, v0, acc0[3]);
      acc1[0] = fmaf(av.x, v1, acc1[0]); acc1[1] = fmaf(av.y, v1, acc1[1]);
      acc1[2] = fmaf(av.z, v1, acc1[2]); acc1[3] = fmaf(av.w, v1, acc1[3]);
    }
    #pragma unroll
    for (int r = 0; r < 4; ++r) {
      #pragma unroll
      for (int off = 1; off < 64; off <<= 1) {
        acc0[r] += __shfl_xor(acc0[r], off);
        acc1[r] += __shfl_xor(acc1[r], off);
      }
    }
    if (l == 0) {
      #pragma unroll
      for (int r = 0; r < 4; ++r) {
        int node = b*NN + i0 + r;
        if (c0 < 16) oout[node*192 + h*16 + c0] = acc0[r];
        else         optout[node*288 + h*24 + (c0-16)] = acc0[r];
        if (c1 < 16) oout[node*192 + h*16 + c1] = acc1[r];
        else         optout[node*288 + h*24 + (c1-16)] = acc1[r];
      }
    }
  }
}

// ---------------- K4a: build feats ----------------
__global__ void k4a_feats(const float* __restrict__ oo, const float* __restrict__ opt,
                          const float* __restrict__ rot, const float* __restrict__ trans,
                          float* __restrict__ feats)
{
  int node = blockIdx.x; int t = threadIdx.x;   // 320 threads
  float* fr = feats + node*576;
  if (t < 192) {
    fr[t] = oo[node*192 + t];
  } else if (t < 288) {
    int hp = t - 192;
    const float* R = rot + node*9;
    float tx = trans[node*3+0]*0.1f, ty = trans[node*3+1]*0.1f, tz = trans[node*3+2]*0.1f;
    const float* op = opt + (node*96 + hp)*3;
    float px = op[0]-tx, py = op[1]-ty, pz = op[2]-tz;
    float lx = R[0]*px + R[3]*py + R[6]*pz;
    float ly = R[1]*px + R[4]*py + R[7]*pz;
    float lz = R[2]*px + R[5]*py + R[8]*pz;
    float d = sqrtf(lx*lx + ly*ly + lz*lz + 1e-8f);
    fr[192+hp] = lx; fr[288+hp] = ly; fr[384+hp] = lz; fr[480+hp] = d;
  }
}

// ---------------- K4b: output projection ----------------
__launch_bounds__(384)
__global__ void k4b_out(const float* __restrict__ feats, const float* __restrict__ Wout,
                        const float* __restrict__ bout, float* __restrict__ sout)
{
  const int ROWS = 8;
  int row0 = blockIdx.x * ROWS;   // grid 128
  int c = threadIdx.x;            // 384
  float acc[ROWS];
  #pragma unroll
  for (int r = 0; r < ROWS; ++r) acc[r] = 0.f;
  #pragma unroll 4
  for (int f = 0; f < 576; ++f) {
    float wv = Wout[f*384 + c];
    #pragma unroll
    for (int r = 0; r < ROWS; ++r)
      acc[r] = fmaf(feats[(row0+r)*576 + f], wv, acc[r]);   // feats uniform -> scalar
  }
  float bb = bout[c];
  #pragma unroll
  for (int r = 0; r < ROWS; ++r) sout[(row0+r)*384 + c] = acc[r] + bb;
}

// ---------------- launch ----------------
extern "C" void kernel_launch(void* const* d_in, const int* in_sizes, int n_in,
                              void* d_out, int out_size, void* d_ws, size_t ws_size,
                              hipStream_t stream)
{
  const float* s     = (const float*)d_in[0];
  const float* rot   = (const float*)d_in[1];
  const float* trans = (const float*)d_in[2];
  const float* mask  = (const float*)d_in[3];
  const float* Wq    = (const float*)d_in[4];
  const float* bq    = (const float*)d_in[5];
  const float* Wkv   = (const float*)d_in[6];
  const float* bkv   = (const float*)d_in[7];
  const float* hwts  = (const float*)d_in[8];
  const float* ln_g  = (const float*)d_in[9];
  const float* ln_b  = (const float*)d_in[10];
  const float* Wpq   = (const float*)d_in[11];
  const float* bpq   = (const float*)d_in[12];
  const float* Wpv   = (const float*)d_in[13];
  const float* bpv   = (const float*)d_in[14];
  const float* Wvl   = (const float*)d_in[15];
  const float* gbm   = (const float*)d_in[16];
  const float* gbs   = (const float*)d_in[17];
  const float* Wg    = (const float*)d_in[18];
  const float* bg    = (const float*)d_in[19];
  const float* W1    = (const float*)d_in[20];
  const float* b1    = (const float*)d_in[21];
  const float* W2    = (const float*)d_in[22];
  const float* b2    = (const float*)d_in[23];
  const float* Wkvp  = (const float*)d_in[24];
  const float* bkvp  = (const float*)d_in[25];
  const float* Wout  = (const float*)d_in[26];
  const float* bout  = (const float*)d_in[27];

  float* ws = (float*)d_ws;
  float* act   = ws + 0;          // 1024*912
  float* Wbig  = ws + 933888;     // 384*912
  float* bias  = ws + 1284096;    // 912
  float* P2    = ws + 1285008;    // 912
  float* W1T   = ws + 1285920;    // 4096
  float* hw    = ws + 1290016;    // 16
  float* mrow  = ws + 1290032;    // 1024
  float* rstd  = ws + 1291056;    // 1024
  float* vT    = ws + 1292080;    // 196608
  float* vgT   = ws + 1488688;    // 294912
  float* apre  = ws + 1783600;    // 6291456
  float* oo    = ws + 8075056;    // 196608
  float* opt   = ws + 8271664;    // 294912
  float* feats = ws + 8566576;    // 589824  (end 9156400 floats = 36.6 MB)

  float* sout = (float*)d_out;
  float* gout = sout + BB*NN*CSZ;   // g at offset 393216

  hipLaunchKernelGGL(k0_prep, dim3(256), dim3(256), 0, stream,
                     Wq, Wkv, Wpq, Wpv, Wkvp, bq, bkv, bpq, bpv, bkvp,
                     ln_g, ln_b, W1, hwts, Wbig, bias, P2, W1T, hw);
  hipLaunchKernelGGL(k0b_stats, dim3(1024), dim3(64), 0, stream, s, mrow, rstd);
  hipLaunchKernelGGL(k1_gemm, dim3(128), dim3(256), 0, stream,
                     s, Wbig, bias, P2, mrow, rstd, act);
  hipLaunchKernelGGL(k1b_post, dim3(1920), dim3(256), 0, stream, act, rot, trans, vT, vgT);
  hipLaunchKernelGGL(k2_pair, dim3(2048), dim3(256), 0, stream,
                     act, rot, trans, mask, Wvl, gbm, gbs, Wg, bg, W1T, b1, W2, b2, hw,
                     gout, apre);
  hipLaunchKernelGGL(k3_attend, dim3(3072), dim3(256), 0, stream, apre, vT, vgT, oo, opt);
  hipLaunchKernelGGL(k4a_feats, dim3(1024), dim3(320), 0, stream, oo, opt, rot, trans, feats);
  hipLaunchKernelGGL(k4b_out, dim3(128), dim3(384), 0, stream, feats, Wout, bout, sout);
}